// Round 4
// baseline (86.205 us; speedup 1.0000x reference)
//
#include <hip/hip_runtime.h>
#include <hip/hip_bf16.h>

static constexpr int NB  = 20;   // N
static constexpr int KK  = 8;    // K
static constexpr int EPT = 4;    // batch elements per thread

typedef float v4f __attribute__((ext_vector_type(4)));

// Round-4: verified round-3 math (event-based k=1 elimination, packed DP) plus:
//  - barrier-free wave-ballot dtype sniff (5 barriers -> 2, no LDS atomics;
//    bit-pack loads issue at kernel start and hide under the softmax phases)
//  - EPT=4: wave-uniform w-reads + loop glue amortized over 4 elements,
//    block count 1024 -> 512 (prologue paid half as often)
__global__ __launch_bounds__(256) void pc_kernel(
    const void* __restrict__ xraw,
    const void* __restrict__ wleaf_raw,
    const void* __restrict__ w2_raw,
    void* __restrict__ outraw,
    int batch)
{
    __shared__ float s_wsm[(NB + 1) * NB];          // exp(Wleaf) — UNSCALED
    __shared__ float s_inv[NB + 1];                 // 1 / rowsum
    __shared__ float s_w20[(KK + 1) * (NB + 1)];    // w2 softmax [...,0]
    __shared__ float s_w21[(KK + 1) * (NB + 1)];    // w2 softmax [...,1]

    const int tid  = threadIdx.x;
    const int lane = tid & 63;

    // ---- barrier-free dtype sniff: every wave computes the same ballots ----
    // (reads match the verified round-0 probe set: x dwords 0..63, W dwords 0..191,
    //  all safe under the smallest dtype interpretation)
    {
        // nothing
    }
    const unsigned xv = ((const unsigned*)xraw)[lane];
    const bool big  = xv > 1u;
    const bool isbf = big && (((xv & 0xFFFFu) == 0x3F80u) || ((xv >> 16) == 0x3F80u));
    const unsigned long long mBig = __ballot(big);
    const unsigned long long mBf  = __ballot(isbf);
    const int fX = mBf ? 2 : (mBig ? 1 : 0);

    unsigned cnt = 0;
    #pragma unroll
    for (int j = 0; j < 3; ++j) {
        const unsigned wv = ((const unsigned*)wleaf_raw)[lane * 3 + j];
        const unsigned hb = (wv >> 8) & 0xFFu;
        cnt += (unsigned)__popcll(__ballot(hb >= 0x30u && hb <= 0x40u));
    }
    const int fW = (cnt > 96u) ? 1 : 0;

    auto WL = [&](int idx) -> float {
        return fW ? __bfloat162float(((const __hip_bfloat16*)wleaf_raw)[idx])
                  : ((const float*)wleaf_raw)[idx];
    };
    auto W2v = [&](int idx) -> float {
        return fW ? __bfloat162float(((const __hip_bfloat16*)w2_raw)[idx])
                  : ((const float*)w2_raw)[idx];
    };

    // ---- bit-pack: global loads issue NOW; latency hides under softmax ----
    const int base = blockIdx.x * (256 * EPT) + tid;
    unsigned bits[EPT];
    bool valid[EPT];
    #pragma unroll
    for (int e = 0; e < EPT; ++e) {
        const int b = base + e * 256;
        valid[e] = (b < batch);
        unsigned bb = 0;
        if (valid[e]) {
            if (fX == 0) {
                const int4* row = (const int4*)((const int*)xraw + (size_t)b * NB);
                #pragma unroll
                for (int j = 0; j < 5; ++j) {
                    int4 v = row[j];
                    bb |= (unsigned)(v.x != 0) << (4 * j + 0);
                    bb |= (unsigned)(v.y != 0) << (4 * j + 1);
                    bb |= (unsigned)(v.z != 0) << (4 * j + 2);
                    bb |= (unsigned)(v.w != 0) << (4 * j + 3);
                }
            } else if (fX == 1) {
                const unsigned* p = (const unsigned*)((const unsigned char*)xraw + (size_t)b * NB);
                #pragma unroll
                for (int j = 0; j < 5; ++j) {
                    unsigned v = p[j];
                    bb |= (unsigned)(((v      ) & 0xFFu) != 0) << (4 * j + 0);
                    bb |= (unsigned)(((v >>  8) & 0xFFu) != 0) << (4 * j + 1);
                    bb |= (unsigned)(((v >> 16) & 0xFFu) != 0) << (4 * j + 2);
                    bb |= (unsigned)(((v >> 24)       ) != 0) << (4 * j + 3);
                }
            } else {
                const unsigned* p = (const unsigned*)((const unsigned short*)xraw + (size_t)b * NB);
                #pragma unroll
                for (int j = 0; j < 10; ++j) {
                    unsigned v = p[j];
                    bb |= (unsigned)((v & 0xFFFFu) != 0) << (2 * j + 0);
                    bb |= (unsigned)((v >> 16)     != 0) << (2 * j + 1);
                }
            }
        }
        bits[e] = bb;
    }

    // ---- softmax prologue, 2 phases / 2 barriers ----
    // Phase A: 210 leaf exp() entries on 200 threads (no max-subtract:
    // exp(w)/sum(exp(w)) identical, weights bounded).
    if (tid < 200) {
        #pragma unroll
        for (int s = 0; s < 2; ++s) {
            const int p = 20 + tid + s * 200;      // p = m*20+i, m=1..20
            const int m = p / 20, i = p - m * 20;
            if (i < m) s_wsm[p] = expf(WL(p));
        }
    }
    __syncthreads();
    // Phase B: row inverse-sums (threads 1..20) + w2 pair softmax (21..209)
    if (tid >= 1 && tid <= NB) {
        float s = 0.f;
        for (int i = 0; i < tid; ++i) s += s_wsm[tid * NB + i];
        s_inv[tid] = 1.f / s;
    } else if (tid >= 21 && tid < 21 + (KK + 1) * (NB + 1)) {
        const int idx = tid - 21;
        const float a = W2v(idx * 2 + 0);
        const float b = W2v(idx * 2 + 1);
        const float mx = fmaxf(a, b);
        const float ea = expf(a - mx), eb = expf(b - mx);
        const float inv = 1.f / (ea + eb);
        s_w20[idx] = ea * inv;
        s_w21[idx] = eb * inv;
    }
    __syncthreads();

    // ---- per-element event extraction (replaces the whole k=1 row) ----
    // j0 = first set bit (0-based), q0 = second set bit (0-based).
    // k=2 injection occurs only at column m = p2 = q0+1 with
    //   inj = w21[2][p2] * wsm[q0][j0] * inv[q0].
    int p2[EPT];
    float inj[EPT];
    #pragma unroll
    for (int e = 0; e < EPT; ++e) {
        const unsigned be = bits[e];
        const unsigned low = be & (be - 1u);       // first set bit removed
        const int j0 = __builtin_ctz(be  | (1u << 20));
        const int q0 = __builtin_ctz(low | (1u << 20));
        const bool has2 = (low != 0u);
        p2[e] = has2 ? (q0 + 1) : 99;              // 1-based col of 2nd set bit
        const int rV = has2 ? q0 : 1;              // safe clamp when <2 bits
        const int cV = has2 ? j0 : 0;
        const float V = s_wsm[rV * NB + cV] * s_inv[rV];
        inj[e] = s_w21[2 * (NB + 1) + (has2 ? (q0 + 1) : 3)] * V;
    }

    // ---- k = 2 row: pure w0 cascade + single injection at m == p2 ----
    v4f S[NB + 1];
    v4f pn;
    #pragma unroll
    for (int e = 0; e < EPT; ++e)
        pn[e] = ((bits[e] & 3u) == 3u) ? 1.f : 0.f;   // base: pre[:,1]
    S[2] = pn;
    #pragma unroll
    for (int m = 3; m <= NB; ++m) {
        const float w0 = s_w20[2 * (NB + 1) + m];
        v4f add;
        #pragma unroll
        for (int e = 0; e < EPT; ++e)
            add[e] = (m == p2[e]) ? inj[e] : 0.f;
        v4f cur = w0 * pn + add;
        S[m] = cur;
        pn = cur;
    }

    // ---- k = 3..K DP, float4-packed across the 4 elements ----
    #pragma unroll
    for (int k = 3; k <= KK; ++k) {
        const unsigned lm = (1u << k) - 1u;
        v4f p, op;
        #pragma unroll
        for (int e = 0; e < EPT; ++e)
            p[e] = ((bits[e] & lm) == lm) ? 1.f : 0.f;   // pre[:, k-1]
        op = S[k];
        S[k] = p;
        #pragma unroll
        for (int m = k + 1; m <= NB; ++m) {
            const v4f oc = S[m];
            const float w0 = s_w20[k * (NB + 1) + m];
            const float w1 = s_w21[k * (NB + 1) + m];
            v4f t;
            #pragma unroll
            for (int e = 0; e < EPT; ++e)
                t[e] = ((bits[e] >> (m - 1)) & 1u) ? op[e] : 0.f;
            v4f cur = w0 * p + w1 * t;
            S[m] = cur;
            p = cur;
            op = oc;
        }
    }

    #pragma unroll
    for (int e = 0; e < EPT; ++e) {
        const int b = base + e * 256;
        if (valid[e]) {
            if (fW) ((__hip_bfloat16*)outraw)[b] = __float2bfloat16(S[NB][e]);
            else    ((float*)outraw)[b]          = S[NB][e];
        }
    }
}

extern "C" void kernel_launch(void* const* d_in, const int* in_sizes, int n_in,
                              void* d_out, int out_size, void* d_ws, size_t ws_size,
                              hipStream_t stream) {
    (void)n_in; (void)out_size; (void)d_ws; (void)ws_size;
    const int batch = in_sizes[0] / NB;                 // 524288
    const int blocks = (batch + 256 * EPT - 1) / (256 * EPT);
    pc_kernel<<<blocks, 256, 0, stream>>>(d_in[0], d_in[1], d_in[2], d_out, batch);
}